// Round 1
// baseline (177.261 us; speedup 1.0000x reference)
//
#include <hip/hip_runtime.h>
#include <hip/hip_bf16.h>
#include <hip/hip_fp8.h>
#include <stdint.h>

// Problem: N=4096 rows, D=768 dims.
//   dist[i][j] = ||A_i - P_j||;  scores = 50 - dist;  loss = mean_i(-log_softmax(scores)_ii)
// Fixed-shift softmax (scores <= 50 always): loss_i = dist_ii + log(sum_j exp(-dist_ij))
// R17 = R16's triple-buffered skeleton (lead-2 vmcnt(4) K-loop) switched to
// MX-scaled fp8 MFMA 32x32x64 (identity E8M0 scales = bit-identical to plain fp8):
//   - 4 MFMA + 8 ds_read_b128 per wave-iter (was 32 MFMA) -> 8x fewer MFMA issues,
//     2x MFMA pipe rate (4686 TF ubench), device MFMA floor 12.6 -> 5.5 us.
//   - New LDS layout for the 32B-per-lane frag: 128B lines = row pairs, 8x16B
//     slots XOR-swizzled by (line&7). Inverse swizzle applied on the GLOBAL source
//     address (linear global_load_lds dest). Each 8-lane phase group of a b128
//     read covers 8 distinct bank groups -> conflict-free.
//   - cvt_norms now writes plain row-major fp8 (coalesced), no granule permute.
//   - XCD-aware bijective block swizzle (1024 blocks): 128 consecutive tiles per
//     XCD -> per-XCD working set ~3.5 MB < 4 MB L2.

#define N_ROWS 4096
#define D_DIM  768
#define NITER (D_DIM / 64)               // 12 (BK=64 fp8 bytes)
#define BUFB  (128 * 64)                 // 8 KB per buffer per matrix

typedef float f32x16 __attribute__((ext_vector_type(16)));
typedef int   i32x4  __attribute__((ext_vector_type(4)));
typedef int   i32x8  __attribute__((ext_vector_type(8)));

// ---------------- kernel 1: fp32 -> fp8 e4m3 cast (row-major) + norms + zero S --
__global__ __launch_bounds__(256) void cvt_norms(
        const float* __restrict__ A, const float* __restrict__ P,
        uint8_t* __restrict__ A8, uint8_t* __restrict__ P8,
        float* __restrict__ a2, float* __restrict__ p2, float* __restrict__ S) {
    const int t = threadIdx.x, lane = t & 63, wave = t >> 6;
    const int row = blockIdx.x * 4 + wave;
    const float* src = blockIdx.y ? P : A;
    uint8_t* dst = blockIdx.y ? P8 : A8;
    float* nrm = blockIdx.y ? p2 : a2;

    const float4* s4 = (const float4*)src + (size_t)row * (D_DIM / 4);
    uint32_t* d4 = (uint32_t*)dst + (size_t)row * (D_DIM / 4);   // row base
    float s = 0.0f;
#pragma unroll
    for (int c = 0; c < 3; c++) {
        const int wf = c * 64 + lane;            // word index in row (0..191)
        float4 v = s4[wf];
        s += v.x * v.x + v.y * v.y + v.z * v.z + v.w * v.w;
        union { uint32_t u; uint8_t b[4]; } pk;
        pk.b[0] = __hip_fp8_e4m3(v.x).__x;
        pk.b[1] = __hip_fp8_e4m3(v.y).__x;
        pk.b[2] = __hip_fp8_e4m3(v.z).__x;
        pk.b[3] = __hip_fp8_e4m3(v.w).__x;
        d4[wf] = pk.u;                           // plain row-major, coalesced
    }
    for (int off = 32; off; off >>= 1) s += __shfl_down(s, off);
    if (lane == 0) {
        nrm[row] = s;
        if (blockIdx.y == 0) S[row] = 0.0f;
    }
}

// ---------------- kernel 2: triple-buffered MX-fp8 MFMA GEMM + softmax epilogue --
__device__ __forceinline__ void g2l16(const void* g, void* l) {
    __builtin_amdgcn_global_load_lds(
        (const __attribute__((address_space(1))) void*)g,
        (__attribute__((address_space(3))) void*)l, 16, 0, 0);
}

__global__ __launch_bounds__(256) void gemm_fused(
        const uint8_t* __restrict__ A8, const uint8_t* __restrict__ P8,
        const float* __restrict__ a2, const float* __restrict__ p2,
        float* __restrict__ S, float* __restrict__ Dd) {
    __shared__ __align__(16) uint8_t As[3 * BUFB];   // 3 x 8 KB
    __shared__ __align__(16) uint8_t Bs[3 * BUFB];   // 3 x 8 KB

    // XCD-aware bijective swizzle: 1024 blocks, 8 XCDs, 128 consecutive per XCD.
    const int lin = blockIdx.x;
    const int swz = (lin & 7) * 128 + (lin >> 3);
    const int bm = swz & 31, bn = swz >> 5;

    const int t = threadIdx.x;
    const int lane = t & 63, wave = t >> 6;
    const int wm = wave >> 1, wn = wave & 1;         // 2x2 waves, 64x64 tiles
    const int r5 = lane & 31, hi = lane >> 5;

    f32x16 acc[2][2];
#pragma unroll
    for (int i = 0; i < 2; i++)
#pragma unroll
        for (int j = 0; j < 2; j++)
#pragma unroll
            for (int r = 0; r < 16; r++) acc[i][j][r] = 0.0f;

    // ---- staging: LDS chunk q (16B) at byte q*16 holds (row R, slot s16) where
    //   line = q>>3, slin = (q&7) ^ (line&7), R = 2*line + (slin>>2), s16 = slin&3.
    // Inverse swizzle on the GLOBAL source address; LDS destination stays linear.
    int srcOff[2];
#pragma unroll
    for (int c = 0; c < 2; c++) {
        const int q = c * 256 + t;
        const int line = q >> 3;
        const int slin = (q & 7) ^ (line & 7);
        const int R = line * 2 + (slin >> 2);
        srcOff[c] = R * D_DIM + (slin & 3) * 16;
    }
    const uint8_t* aG = A8 + (size_t)bm * 128 * D_DIM;
    const uint8_t* bG = P8 + (size_t)bn * 128 * D_DIM;

    // ---- LDS->frag read offsets (bytes). Lane (r5,hi) frag mi: row R = wm*64+
    // mi*32+r5, K-bytes hi*32..hi*32+31 = two b128 reads p=0,1 at
    //   addr = (R>>1)*128 + (((R&1)*4 + hi*2 + p) ^ ((R>>1)&7)) * 16.
    int aOff[2][2], bOff[2][2];
#pragma unroll
    for (int mi = 0; mi < 2; mi++) {
        const int R = wm * 64 + mi * 32 + r5;
        const int line = R >> 1;
        const int slb = (R & 1) * 4 + hi * 2;
#pragma unroll
        for (int p = 0; p < 2; p++)
            aOff[mi][p] = line * 128 + (((slb + p) ^ (line & 7)) << 4);
    }
#pragma unroll
    for (int ni = 0; ni < 2; ni++) {
        const int R = wn * 64 + ni * 32 + r5;
        const int line = R >> 1;
        const int slb = (R & 1) * 4 + hi * 2;
#pragma unroll
        for (int p = 0; p < 2; p++)
            bOff[ni][p] = line * 128 + (((slb + p) ^ (line & 7)) << 4);
    }

#define STAGE(K2, SEL)                                                            \
    do {                                                                          \
        const int k0_ = (K2) * 64;                                                \
        const int lb_ = (SEL) * BUFB;                                             \
        _Pragma("unroll")                                                         \
        for (int c = 0; c < 2; c++)                                               \
            g2l16(aG + srcOff[c] + k0_, &As[lb_ + (c * 256 + t) * 16]);           \
        _Pragma("unroll")                                                         \
        for (int c = 0; c < 2; c++)                                               \
            g2l16(bG + srcOff[c] + k0_, &Bs[lb_ + (c * 256 + t) * 16]);           \
    } while (0)

    STAGE(0, 0);
    STAGE(1, 1);

    const int SCALE1 = 0x7f7f7f7f;                   // E8M0 identity (2^0) x4

    int s0 = 0;                                      // buffer holding tile k
    for (int k = 0; k < NITER; k++) {
        // Drain tile k's 4 loads (issued at iter k-2); tile k+1's stay in flight.
        if (k == NITER - 1) asm volatile("s_waitcnt vmcnt(0)" ::: "memory");
        else                asm volatile("s_waitcnt vmcnt(4)" ::: "memory");
        asm volatile("s_barrier" ::: "memory");
        if (k + 2 < NITER) {
            int s2 = s0 + 2; if (s2 >= 3) s2 -= 3;
            STAGE(k + 2, s2);                        // WAR-safe: buf read at k-1
        }

        const int lb = s0 * BUFB;
        i32x8 af[2], bf[2];
#pragma unroll
        for (int mi = 0; mi < 2; mi++) {
            const i32x4 lo = *(const i32x4*)&As[lb + aOff[mi][0]];
            const i32x4 hi4 = *(const i32x4*)&As[lb + aOff[mi][1]];
            af[mi][0] = lo[0]; af[mi][1] = lo[1]; af[mi][2] = lo[2]; af[mi][3] = lo[3];
            af[mi][4] = hi4[0]; af[mi][5] = hi4[1]; af[mi][6] = hi4[2]; af[mi][7] = hi4[3];
        }
#pragma unroll
        for (int ni = 0; ni < 2; ni++) {
            const i32x4 lo = *(const i32x4*)&Bs[lb + bOff[ni][0]];
            const i32x4 hi4 = *(const i32x4*)&Bs[lb + bOff[ni][1]];
            bf[ni][0] = lo[0]; bf[ni][1] = lo[1]; bf[ni][2] = lo[2]; bf[ni][3] = lo[3];
            bf[ni][4] = hi4[0]; bf[ni][5] = hi4[1]; bf[ni][6] = hi4[2]; bf[ni][7] = hi4[3];
        }
#pragma unroll
        for (int mi = 0; mi < 2; mi++)
#pragma unroll
            for (int ni = 0; ni < 2; ni++)
                acc[mi][ni] = __builtin_amdgcn_mfma_scale_f32_32x32x64_f8f6f4(
                    af[mi], bf[ni], acc[mi][ni], 0, 0, 0, SCALE1, 0, SCALE1);
        s0 = (s0 == 2) ? 0 : s0 + 1;
    }
#undef STAGE

    // ---- epilogue: dist -> exp(-dist), per-row partial sums, diagonal capture ----
    // C/D layout (32x32): col = lane&31, row = (reg&3) + 8*(reg>>2) + 4*(lane>>5)
    float p2v[2];
#pragma unroll
    for (int ni = 0; ni < 2; ni++)
        p2v[ni] = p2[bn * 128 + wn * 64 + ni * 32 + r5];
    const int colBase = bn * 128 + wn * 64 + r5;

#pragma unroll
    for (int mi = 0; mi < 2; mi++) {
#pragma unroll
        for (int reg = 0; reg < 16; reg++) {
            const int gi = bm * 128 + wm * 64 + mi * 32 +
                           (reg & 3) + 8 * (reg >> 2) + 4 * hi;
            const float a2v = a2[gi];
            float rs = 0.0f;
#pragma unroll
            for (int ni = 0; ni < 2; ni++) {
                const float cross = acc[mi][ni][reg];
                const float sq = a2v + p2v[ni] - 2.0f * cross;
                const float dist = sqrtf(fmaxf(sq, 0.0f) + 1e-12f);
                const int gj = colBase + ni * 32;
                if (gi == gj) Dd[gi] = dist;
                rs += __expf(-dist);
            }
            rs += __shfl_xor(rs, 1);
            rs += __shfl_xor(rs, 2);
            rs += __shfl_xor(rs, 4);
            rs += __shfl_xor(rs, 8);
            rs += __shfl_xor(rs, 16);
            if (r5 == 0) atomicAdd(&S[gi], rs);
        }
    }
}

// ---------------- kernel 3: final reduce -> scalar -------------------------------
__global__ void finalize(const float* __restrict__ S, const float* __restrict__ Dd,
                         float* __restrict__ out) {
    const int t = threadIdx.x;
    float s = 0.0f;
    for (int i = t; i < N_ROWS; i += 256) s += Dd[i] + logf(S[i]);
    for (int off = 32; off; off >>= 1) s += __shfl_down(s, off);
    __shared__ float wsum[4];
    if ((t & 63) == 0) wsum[t >> 6] = s;
    __syncthreads();
    if (t == 0) out[0] = (wsum[0] + wsum[1] + wsum[2] + wsum[3]) * (1.0f / N_ROWS);
}

// ---------------- fallback (undersized workspace): naive fp32 --------------------
__global__ void zero_out1(float* __restrict__ out) {
    if (threadIdx.x == 0 && blockIdx.x == 0) out[0] = 0.0f;
}
__global__ void naive_row(const float* __restrict__ A, const float* __restrict__ P,
                          float* __restrict__ out) {
    __shared__ float arow[D_DIM];
    const int i = blockIdx.x, t = threadIdx.x;
    for (int c = t; c < D_DIM; c += 256) arow[c] = A[(size_t)i * D_DIM + c];
    __syncthreads();
    float sumexp = 0.0f, ddiag = 0.0f;
    for (int j = t; j < N_ROWS; j += 256) {
        const float* p = P + (size_t)j * D_DIM;
        float d2 = 0.0f;
        for (int c = 0; c < D_DIM; c++) { float df = arow[c] - p[c]; d2 += df * df; }
        float dist = sqrtf(fmaxf(d2, 0.0f) + 1e-12f);
        if (j == i) ddiag = dist;
        sumexp += __expf(-dist);
    }
    for (int off = 32; off; off >>= 1) {
        sumexp += __shfl_down(sumexp, off);
        ddiag  += __shfl_down(ddiag, off);
    }
    __shared__ float w1[4], w2[4];
    if ((t & 63) == 0) { w1[t >> 6] = sumexp; w2[t >> 6] = ddiag; }
    __syncthreads();
    if (t == 0) {
        float se = w1[0] + w1[1] + w1[2] + w1[3];
        float dd = w2[0] + w2[1] + w2[2] + w2[3];
        atomicAdd(out, (dd + logf(se)) * (1.0f / N_ROWS));
    }
}

extern "C" void kernel_launch(void* const* d_in, const int* in_sizes, int n_in,
                              void* d_out, int out_size, void* d_ws, size_t ws_size,
                              hipStream_t stream) {
    const float* A = (const float*)d_in[0];
    const float* P = (const float*)d_in[1];
    float* out = (float*)d_out;

    const size_t F8_BYTES = (size_t)N_ROWS * D_DIM;          // 3145728 per matrix
    const size_t V_BYTES  = (size_t)N_ROWS * sizeof(float);  // 16384
    const size_t NEED = 2 * F8_BYTES + 4 * V_BYTES;

    if (ws_size >= NEED) {
        char* ws = (char*)d_ws;
        uint8_t* A8 = (uint8_t*)(ws);
        uint8_t* P8 = (uint8_t*)(ws + F8_BYTES);
        float* a2 = (float*)(ws + 2 * F8_BYTES);
        float* p2 = (float*)(ws + 2 * F8_BYTES + V_BYTES);
        float* S  = (float*)(ws + 2 * F8_BYTES + 2 * V_BYTES);
        float* Dd = (float*)(ws + 2 * F8_BYTES + 3 * V_BYTES);

        hipLaunchKernelGGL(cvt_norms, dim3(N_ROWS / 4, 2), dim3(256), 0, stream,
                           A, P, A8, P8, a2, p2, S);
        hipLaunchKernelGGL(gemm_fused, dim3(32 * 32), dim3(256), 0, stream,
                           A8, P8, a2, p2, S, Dd);
        hipLaunchKernelGGL(finalize, dim3(1), dim3(256), 0, stream, S, Dd, out);
    } else {
        hipLaunchKernelGGL(zero_out1, dim3(1), dim3(64), 0, stream, out);
        hipLaunchKernelGGL(naive_row, dim3(N_ROWS), dim3(256), 0, stream, A, P, out);
    }
}

// Round 2
// 112.477 us; speedup vs baseline: 1.5760x; 1.5760x over previous
//
#include <hip/hip_runtime.h>
#include <hip/hip_bf16.h>
#include <hip/hip_fp8.h>
#include <stdint.h>

// Problem: N=4096 rows, D=768 dims.
//   dist[i][j] = ||A_i - P_j||;  scores = 50 - dist;  loss = mean_i(-log_softmax(scores)_ii)
// Fixed-shift softmax (scores <= 50 always): loss_i = dist_ii + log(sum_j exp(-dist_ij))
// R18 = R16 (proven: fp8 16x16x32, 128x128 block, 64x64 wave tiles, conflict-free
// 64B-row LDS ADD-swizzle, triple-buffered lead-2 vmcnt(4) K-loop) + two knobs:
//   - __launch_bounds__(256,3): force VGPR<=~170 -> 3 waves/SIMD -> 3 blocks/CU
//     (LDS 3x48KB=144<=160KB). R17 post-mortem: 184 VGPR -> 2 blocks/CU was the
//     occupancy cliff (10.3% measured); per-iter stalls had nothing to overlap.
//   - XCD-bijective block swizzle (1024%8==0): per-XCD working set = all A (3MB)
//     + 4 P-panels (0.4MB) = 3.4MB < 4MB L2 (vs 6.3MB thrash unswizzled).

#define N_ROWS 4096
#define D_DIM  768
#define NITER (D_DIM / 64)               // 12 (BK=64 fp8 bytes)
#define BUFB  (128 * 64)                 // 8 KB per buffer per matrix

typedef float f32x4 __attribute__((ext_vector_type(4)));
typedef int   i32x4 __attribute__((ext_vector_type(4)));

// ---------------- kernel 1: fp32 -> fp8 e4m3 cast (k-permuted) + norms + zero S --
// Within each 64B block (16 words): granule gw = w>>1 -> gp = ((gw&3)<<1)|(gw>>2).
__global__ __launch_bounds__(256) void cvt_norms(
        const float* __restrict__ A, const float* __restrict__ P,
        uint8_t* __restrict__ A8, uint8_t* __restrict__ P8,
        float* __restrict__ a2, float* __restrict__ p2, float* __restrict__ S) {
    const int t = threadIdx.x, lane = t & 63, wave = t >> 6;
    const int row = blockIdx.x * 4 + wave;
    const float* src = blockIdx.y ? P : A;
    uint8_t* dst = blockIdx.y ? P8 : A8;
    float* nrm = blockIdx.y ? p2 : a2;

    const float4* s4 = (const float4*)src + (size_t)row * (D_DIM / 4);
    uint32_t* d4 = (uint32_t*)dst + (size_t)row * (D_DIM / 4);   // row base
    float s = 0.0f;
#pragma unroll
    for (int c = 0; c < 3; c++) {
        const int wf = c * 64 + lane;            // word index in row (0..191)
        float4 v = s4[wf];
        s += v.x * v.x + v.y * v.y + v.z * v.z + v.w * v.w;
        union { uint32_t u; uint8_t b[4]; } pk;
        pk.b[0] = __hip_fp8_e4m3(v.x).__x;
        pk.b[1] = __hip_fp8_e4m3(v.y).__x;
        pk.b[2] = __hip_fp8_e4m3(v.z).__x;
        pk.b[3] = __hip_fp8_e4m3(v.w).__x;
        const int kb = wf >> 4, w16 = wf & 15;
        const int gw = w16 >> 1, h = w16 & 1;
        const int gp = ((gw & 3) << 1) | (gw >> 2);     // [0,4,1,5,2,6,3,7] order
        d4[(kb << 4) + (gp << 1) + h] = pk.u;           // relative to row base
    }
    for (int off = 32; off; off >>= 1) s += __shfl_down(s, off);
    if (lane == 0) {
        nrm[row] = s;
        if (blockIdx.y == 0) S[row] = 0.0f;
    }
}

// ---------------- kernel 2: triple-buffered fp8 MFMA GEMM + softmax epilogue -----
__device__ __forceinline__ void g2l16(const void* g, void* l) {
    __builtin_amdgcn_global_load_lds(
        (const __attribute__((address_space(1))) void*)g,
        (__attribute__((address_space(3))) void*)l, 16, 0, 0);
}

__global__ __launch_bounds__(256, 3) void gemm_fused(
        const uint8_t* __restrict__ A8, const uint8_t* __restrict__ P8,
        const float* __restrict__ a2, const float* __restrict__ p2,
        float* __restrict__ S, float* __restrict__ Dd) {
    __shared__ __align__(16) uint8_t As[3 * BUFB];   // 3 x 8 KB
    __shared__ __align__(16) uint8_t Bs[3 * BUFB];   // 3 x 8 KB

    // XCD-bijective swizzle: 1024 blocks round-robin across 8 XCDs; give XCD x
    // the contiguous swz range [x*128, (x+1)*128) = 4 P-panels x all A-panels.
    const int lin = blockIdx.x;
    const int swz = (lin & 7) * 128 + (lin >> 3);
    const int bm = swz & 31, bn = swz >> 5;

    const int t = threadIdx.x;
    const int lane = t & 63, wave = t >> 6;
    const int wm = wave >> 1, wn = wave & 1;   // 2x2 waves, 64x64 tiles

    f32x4 acc[4][4];
#pragma unroll
    for (int i = 0; i < 4; i++)
#pragma unroll
        for (int j = 0; j < 4; j++) acc[i][j] = (f32x4){0.f, 0.f, 0.f, 0.f};

    // staging: physical 16B chunk p = c*256+t -> LDS row r = c*64 + (t>>2),
    // slot s = t&3. Stored global chunk g: s = (g + (r>>1))&3
    //   -> g = ((t&3) - (t>>3)) & 3   (c-invariant: c*32 % 4 == 0).
    const int gT = ((t & 3) - (t >> 3)) & 3;
    const size_t aBase = (size_t)(bm * 128 + (t >> 2)) * D_DIM + (size_t)gT * 16;
    const size_t bBase = (size_t)(bn * 128 + (t >> 2)) * D_DIM + (size_t)gT * 16;

    // LDS->frag read offsets (bytes). Row stride 64 B. Lane quad fq reads stored
    // chunk fq of its row at slot (fq + (R>>1))&3; b128 low 8B = k-step0 granule,
    // high 8B = k-step1 granule. Measured 0 conflicts (R14/R15).
    const int fr = lane & 15, fq = lane >> 4;
    int aOff[4], bOff[4];
#pragma unroll
    for (int mi = 0; mi < 4; mi++) {
        const int R = wm * 64 + mi * 16 + fr;
        aOff[mi] = R * 64 + ((fq + (R >> 1)) & 3) * 16;
    }
#pragma unroll
    for (int ni = 0; ni < 4; ni++) {
        const int R = wn * 64 + ni * 16 + fr;
        bOff[ni] = R * 64 + ((fq + (R >> 1)) & 3) * 16;
    }

#define STAGE(K2, SEL)                                                            \
    do {                                                                          \
        const int k0_ = (K2) * 64;                                                \
        const int lb_ = (SEL) * BUFB;                                             \
        _Pragma("unroll")                                                         \
        for (int c = 0; c < 2; c++)                                               \
            g2l16(A8 + aBase + (size_t)c * (64 * D_DIM) + k0_,                    \
                  &As[lb_ + (c * 256 + t) * 16]);                                 \
        _Pragma("unroll")                                                         \
        for (int c = 0; c < 2; c++)                                               \
            g2l16(P8 + bBase + (size_t)c * (64 * D_DIM) + k0_,                    \
                  &Bs[lb_ + (c * 256 + t) * 16]);                                 \
    } while (0)

    STAGE(0, 0);
    STAGE(1, 1);

    int s0 = 0;                                  // buffer holding tile k
    for (int k = 0; k < NITER; k++) {
        // Drain tile k's 4 loads (issued at iter k-2, ~2 iterations of lead);
        // tile k+1's 4 loads stay in flight across the barrier.
        if (k == NITER - 1) asm volatile("s_waitcnt vmcnt(0)" ::: "memory");
        else                asm volatile("s_waitcnt vmcnt(4)" ::: "memory");
        asm volatile("s_barrier" ::: "memory");
        if (k + 2 < NITER) {
            int s2 = s0 + 2; if (s2 >= 3) s2 -= 3;
            STAGE(k + 2, s2);                    // WAR-safe: buf read in iter k-1
        }

        const int lb = s0 * BUFB;
        i32x4 av[4], bv[4];
#pragma unroll
        for (int mi = 0; mi < 4; mi++)
            av[mi] = *(const i32x4*)&As[lb + aOff[mi]];
#pragma unroll
        for (int ni = 0; ni < 4; ni++)
            bv[ni] = *(const i32x4*)&Bs[lb + bOff[ni]];
#pragma unroll
        for (int step = 0; step < 2; step++) {
#pragma unroll
            for (int mi = 0; mi < 4; mi++) {
                const long long afh = ((const long long*)&av[mi])[step];
#pragma unroll
                for (int ni = 0; ni < 4; ni++) {
                    const long long bfh = ((const long long*)&bv[ni])[step];
                    acc[mi][ni] = __builtin_amdgcn_mfma_f32_16x16x32_fp8_fp8(
                        afh, bfh, acc[mi][ni], 0, 0, 0);
                }
            }
        }
        s0 = (s0 == 2) ? 0 : s0 + 1;
    }
#undef STAGE

    // ---- epilogue: dist -> exp(-dist), per-row partial sums, diagonal capture ----
    // C/D layout (16x16, shape-determined): col = lane&15, row = (lane>>4)*4 + reg
    float p2v[4];
#pragma unroll
    for (int ni = 0; ni < 4; ni++)
        p2v[ni] = p2[bn * 128 + wn * 64 + ni * 16 + fr];
    const int colBase = bn * 128 + wn * 64 + fr;

#pragma unroll
    for (int mi = 0; mi < 4; mi++) {
#pragma unroll
        for (int r = 0; r < 4; r++) {
            const int gi = bm * 128 + wm * 64 + mi * 16 + fq * 4 + r;
            const float a2v = a2[gi];
            float rs = 0.0f;
#pragma unroll
            for (int ni = 0; ni < 4; ni++) {
                const float cross = acc[mi][ni][r];
                const float sq = a2v + p2v[ni] - 2.0f * cross;
                const float dist = sqrtf(fmaxf(sq, 0.0f) + 1e-12f);
                const int gj = colBase + ni * 16;
                if (gi == gj) Dd[gi] = dist;
                rs += __expf(-dist);
            }
            rs += __shfl_xor(rs, 1);
            rs += __shfl_xor(rs, 2);
            rs += __shfl_xor(rs, 4);
            rs += __shfl_xor(rs, 8);
            if (fr == 0) atomicAdd(&S[gi], rs);
        }
    }
}

// ---------------- kernel 3: final reduce -> scalar -------------------------------
__global__ __launch_bounds__(1024) void finalize(
        const float* __restrict__ S, const float* __restrict__ Dd,
        float* __restrict__ out) {
    const int t = threadIdx.x;
    float s = 0.0f;
    for (int i = t; i < N_ROWS; i += 1024) s += Dd[i] + logf(S[i]);
    for (int off = 32; off; off >>= 1) s += __shfl_down(s, off);
    __shared__ float wsum[16];
    if ((t & 63) == 0) wsum[t >> 6] = s;
    __syncthreads();
    if (t == 0) {
        float acc = 0.0f;
#pragma unroll
        for (int w = 0; w < 16; w++) acc += wsum[w];
        out[0] = acc * (1.0f / N_ROWS);
    }
}

// ---------------- fallback (undersized workspace): naive fp32 --------------------
__global__ void zero_out1(float* __restrict__ out) {
    if (threadIdx.x == 0 && blockIdx.x == 0) out[0] = 0.0f;
}
__global__ void naive_row(const float* __restrict__ A, const float* __restrict__ P,
                          float* __restrict__ out) {
    __shared__ float arow[D_DIM];
    const int i = blockIdx.x, t = threadIdx.x;
    for (int c = t; c < D_DIM; c += 256) arow[c] = A[(size_t)i * D_DIM + c];
    __syncthreads();
    float sumexp = 0.0f, ddiag = 0.0f;
    for (int j = t; j < N_ROWS; j += 256) {
        const float* p = P + (size_t)j * D_DIM;
        float d2 = 0.0f;
        for (int c = 0; c < D_DIM; c++) { float df = arow[c] - p[c]; d2 += df * df; }
        float dist = sqrtf(fmaxf(d2, 0.0f) + 1e-12f);
        if (j == i) ddiag = dist;
        sumexp += __expf(-dist);
    }
    for (int off = 32; off; off >>= 1) {
        sumexp += __shfl_down(sumexp, off);
        ddiag  += __shfl_down(ddiag, off);
    }
    __shared__ float w1[4], w2[4];
    if ((t & 63) == 0) { w1[t >> 6] = sumexp; w2[t >> 6] = ddiag; }
    __syncthreads();
    if (t == 0) {
        float se = w1[0] + w1[1] + w1[2] + w1[3];
        float dd = w2[0] + w2[1] + w2[2] + w2[3];
        atomicAdd(out, (dd + logf(se)) * (1.0f / N_ROWS));
    }
}

extern "C" void kernel_launch(void* const* d_in, const int* in_sizes, int n_in,
                              void* d_out, int out_size, void* d_ws, size_t ws_size,
                              hipStream_t stream) {
    const float* A = (const float*)d_in[0];
    const float* P = (const float*)d_in[1];
    float* out = (float*)d_out;

    const size_t F8_BYTES = (size_t)N_ROWS * D_DIM;          // 3145728 per matrix
    const size_t V_BYTES  = (size_t)N_ROWS * sizeof(float);  // 16384
    const size_t NEED = 2 * F8_BYTES + 4 * V_BYTES;

    if (ws_size >= NEED) {
        char* ws = (char*)d_ws;
        uint8_t* A8 = (uint8_t*)(ws);
        uint8_t* P8 = (uint8_t*)(ws + F8_BYTES);
        float* a2 = (float*)(ws + 2 * F8_BYTES);
        float* p2 = (float*)(ws + 2 * F8_BYTES + V_BYTES);
        float* S  = (float*)(ws + 2 * F8_BYTES + 2 * V_BYTES);
        float* Dd = (float*)(ws + 2 * F8_BYTES + 3 * V_BYTES);

        hipLaunchKernelGGL(cvt_norms, dim3(N_ROWS / 4, 2), dim3(256), 0, stream,
                           A, P, A8, P8, a2, p2, S);
        hipLaunchKernelGGL(gemm_fused, dim3(1024), dim3(256), 0, stream,
                           A8, P8, a2, p2, S, Dd);
        hipLaunchKernelGGL(finalize, dim3(1), dim3(1024), 0, stream, S, Dd, out);
    } else {
        hipLaunchKernelGGL(zero_out1, dim3(1), dim3(64), 0, stream, out);
        hipLaunchKernelGGL(naive_row, dim3(N_ROWS), dim3(256), 0, stream, A, P, out);
    }
}

// Round 5
// 101.683 us; speedup vs baseline: 1.7433x; 1.1062x over previous
//
#include <hip/hip_runtime.h>
#include <hip/hip_bf16.h>
#include <hip/hip_fp8.h>
#include <stdint.h>

// Problem: N=4096 rows, D=768 dims.
//   dist[i][j] = ||A_i - P_j||;  scores = 50 - dist;  loss = mean_i(-log_softmax(scores)_ii)
// Fixed-shift softmax (scores <= 50 always): loss_i = dist_ii + log(sum_j exp(-dist_ij))
// R21 = R19 resubmitted verbatim (R19/R20 benches failed on GPU acquisition).
// R19 = R18's proven per-wave math (fp8 16x16x32, 64x64 wave tiles, conflict-free
// 64B-row LDS ADD-swizzle, triple-buffered lead-2 counted-vmcnt K-loop) reshaped to
// a 256x128 block with 8 waves (512 thr, wave grid 4m x 2n):
//   - LDS 3x(16K A + 8K B) = 72 KB -> exactly 2 blocks/CU (144<=160 KB).
//   - 512 blocks = exactly 2 resident per CU -> 16 waves/CU (50% occ), no
//     sequential block rounds (R18: 4 rounds, 20.7% occ, ~70% stall).
//   - STAGE = 3 loads (2A+1B) -> per-iter wait vmcnt(3) (drain tile k only).
//   - XCD swizzle: 64 consecutive swz per XCD -> all A (3MB) + 4 B-panels < 4MB L2.

#define N_ROWS 4096
#define D_DIM  768
#define NITER (D_DIM / 64)               // 12 (BK=64 fp8 bytes)
#define ABUF  (256 * 64)                 // 16 KB per buffer (A)
#define BBUF  (128 * 64)                 // 8 KB per buffer (B)

typedef float f32x4 __attribute__((ext_vector_type(4)));
typedef int   i32x4 __attribute__((ext_vector_type(4)));

// ---------------- kernel 1: fp32 -> fp8 e4m3 cast (k-permuted) + norms + zero S --
// Within each 64B block (16 words): granule gw = w>>1 -> gp = ((gw&3)<<1)|(gw>>2).
__global__ __launch_bounds__(256) void cvt_norms(
        const float* __restrict__ A, const float* __restrict__ P,
        uint8_t* __restrict__ A8, uint8_t* __restrict__ P8,
        float* __restrict__ a2, float* __restrict__ p2, float* __restrict__ S) {
    const int t = threadIdx.x, lane = t & 63, wave = t >> 6;
    const int row = blockIdx.x * 4 + wave;
    const float* src = blockIdx.y ? P : A;
    uint8_t* dst = blockIdx.y ? P8 : A8;
    float* nrm = blockIdx.y ? p2 : a2;

    const float4* s4 = (const float4*)src + (size_t)row * (D_DIM / 4);
    uint32_t* d4 = (uint32_t*)dst + (size_t)row * (D_DIM / 4);   // row base
    float s = 0.0f;
#pragma unroll
    for (int c = 0; c < 3; c++) {
        const int wf = c * 64 + lane;            // word index in row (0..191)
        float4 v = s4[wf];
        s += v.x * v.x + v.y * v.y + v.z * v.z + v.w * v.w;
        union { uint32_t u; uint8_t b[4]; } pk;
        pk.b[0] = __hip_fp8_e4m3(v.x).__x;
        pk.b[1] = __hip_fp8_e4m3(v.y).__x;
        pk.b[2] = __hip_fp8_e4m3(v.z).__x;
        pk.b[3] = __hip_fp8_e4m3(v.w).__x;
        const int kb = wf >> 4, w16 = wf & 15;
        const int gw = w16 >> 1, h = w16 & 1;
        const int gp = ((gw & 3) << 1) | (gw >> 2);     // [0,4,1,5,2,6,3,7] order
        d4[(kb << 4) + (gp << 1) + h] = pk.u;           // relative to row base
    }
    for (int off = 32; off; off >>= 1) s += __shfl_down(s, off);
    if (lane == 0) {
        nrm[row] = s;
        if (blockIdx.y == 0) S[row] = 0.0f;
    }
}

// ---------------- kernel 2: triple-buffered fp8 MFMA GEMM + softmax epilogue -----
__device__ __forceinline__ void g2l16(const void* g, void* l) {
    __builtin_amdgcn_global_load_lds(
        (const __attribute__((address_space(1))) void*)g,
        (__attribute__((address_space(3))) void*)l, 16, 0, 0);
}

__global__ __launch_bounds__(512, 4) void gemm_fused(
        const uint8_t* __restrict__ A8, const uint8_t* __restrict__ P8,
        const float* __restrict__ a2, const float* __restrict__ p2,
        float* __restrict__ S, float* __restrict__ Dd) {
    __shared__ __align__(16) uint8_t As[3 * ABUF];   // 3 x 16 KB
    __shared__ __align__(16) uint8_t Bs[3 * BBUF];   // 3 x 8 KB

    // XCD-bijective swizzle: 512 blocks round-robin across 8 XCDs; XCD x gets the
    // contiguous swz range [x*64,(x+1)*64) = 4 B-panels x all 16 A-panels.
    const int lin = blockIdx.x;
    const int swz = (lin & 7) * 64 + (lin >> 3);
    const int bm = swz & 15, bn = swz >> 4;          // bm: 256-row A panel, bn: 128-row B panel

    const int t = threadIdx.x;
    const int lane = t & 63, wave = t >> 6;          // 8 waves
    const int wm = wave >> 1, wn = wave & 1;         // 4x2 waves, 64x64 tiles

    f32x4 acc[4][4];
#pragma unroll
    for (int i = 0; i < 4; i++)
#pragma unroll
        for (int j = 0; j < 4; j++) acc[i][j] = (f32x4){0.f, 0.f, 0.f, 0.f};

    // staging: chunk q = c*512 + t -> LDS row r = q>>2 = c*128 + (t>>2), slot t&3.
    // Stored global chunk g: slot = (g + (r>>1))&3 -> g = ((t&3) - (t>>3)) & 3
    // (c-invariant: c*128 rows -> (r>>1) shifts by 64 == 0 mod 4).
    const int gT = ((t & 3) - (t >> 3)) & 3;
    const size_t aBase = (size_t)(bm * 256 + (t >> 2)) * D_DIM + (size_t)gT * 16;
    const size_t bBase = (size_t)(bn * 128 + (t >> 2)) * D_DIM + (size_t)gT * 16;

    // LDS->frag read offsets (bytes). Row stride 64 B. Lane quad fq reads stored
    // chunk fq of its row at slot (fq + (R>>1))&3; b128 low 8B = k-step0 granule,
    // high 8B = k-step1 granule. Measured 0 conflicts (R14/R15/R18).
    const int fr = lane & 15, fq = lane >> 4;
    int aOff[4], bOff[4];
#pragma unroll
    for (int mi = 0; mi < 4; mi++) {
        const int R = wm * 64 + mi * 16 + fr;        // 0..255
        aOff[mi] = R * 64 + ((fq + (R >> 1)) & 3) * 16;
    }
#pragma unroll
    for (int ni = 0; ni < 4; ni++) {
        const int R = wn * 64 + ni * 16 + fr;        // 0..127
        bOff[ni] = R * 64 + ((fq + (R >> 1)) & 3) * 16;
    }

#define STAGE(K2, SEL)                                                            \
    do {                                                                          \
        const int k0_ = (K2) * 64;                                                \
        _Pragma("unroll")                                                         \
        for (int c = 0; c < 2; c++)                                               \
            g2l16(A8 + aBase + (size_t)c * (128 * D_DIM) + k0_,                   \
                  &As[(SEL) * ABUF + (c * 512 + t) * 16]);                        \
        g2l16(P8 + bBase + k0_, &Bs[(SEL) * BBUF + t * 16]);                      \
    } while (0)

    STAGE(0, 0);
    STAGE(1, 1);

    int s0 = 0;                                  // buffer holding tile k
    for (int k = 0; k < NITER; k++) {
        // Drain tile k's 3 loads (issued at iter k-2, ~2 iterations of lead);
        // tile k+1's 3 loads stay in flight across the barrier.
        if (k == NITER - 1) asm volatile("s_waitcnt vmcnt(0)" ::: "memory");
        else                asm volatile("s_waitcnt vmcnt(3)" ::: "memory");
        asm volatile("s_barrier" ::: "memory");
        if (k + 2 < NITER) {
            int s2 = s0 + 2; if (s2 >= 3) s2 -= 3;
            STAGE(k + 2, s2);                    // WAR-safe: buf read in iter k-1
        }

        const int lbA = s0 * ABUF, lbB = s0 * BBUF;
        i32x4 av[4], bv[4];
#pragma unroll
        for (int mi = 0; mi < 4; mi++)
            av[mi] = *(const i32x4*)&As[lbA + aOff[mi]];
#pragma unroll
        for (int ni = 0; ni < 4; ni++)
            bv[ni] = *(const i32x4*)&Bs[lbB + bOff[ni]];
#pragma unroll
        for (int step = 0; step < 2; step++) {
#pragma unroll
            for (int mi = 0; mi < 4; mi++) {
                const long long afh = ((const long long*)&av[mi])[step];
#pragma unroll
                for (int ni = 0; ni < 4; ni++) {
                    const long long bfh = ((const long long*)&bv[ni])[step];
                    acc[mi][ni] = __builtin_amdgcn_mfma_f32_16x16x32_fp8_fp8(
                        afh, bfh, acc[mi][ni], 0, 0, 0);
                }
            }
        }
        s0 = (s0 == 2) ? 0 : s0 + 1;
    }
#undef STAGE

    // ---- epilogue: dist -> exp(-dist), per-row partial sums, diagonal capture ----
    // C/D layout (16x16, shape-determined): col = lane&15, row = (lane>>4)*4 + reg
    float p2v[4];
#pragma unroll
    for (int ni = 0; ni < 4; ni++)
        p2v[ni] = p2[bn * 128 + wn * 64 + ni * 16 + fr];
    const int colBase = bn * 128 + wn * 64 + fr;

#pragma unroll
    for (int mi = 0; mi < 4; mi++) {
#pragma unroll
        for (int r = 0; r < 4; r++) {
            const int gi = bm * 256 + wm * 64 + mi * 16 + fq * 4 + r;
            const float a2v = a2[gi];
            float rs = 0.0f;
#pragma unroll
            for (int ni = 0; ni < 4; ni++) {
                const float cross = acc[mi][ni][r];
                const float sq = a2v + p2v[ni] - 2.0f * cross;
                const float dist = sqrtf(fmaxf(sq, 0.0f) + 1e-12f);
                const int gj = colBase + ni * 16;
                if (gi == gj) Dd[gi] = dist;
                rs += __expf(-dist);
            }
            rs += __shfl_xor(rs, 1);
            rs += __shfl_xor(rs, 2);
            rs += __shfl_xor(rs, 4);
            rs += __shfl_xor(rs, 8);
            if (fr == 0) atomicAdd(&S[gi], rs);
        }
    }
}

// ---------------- kernel 3: final reduce -> scalar -------------------------------
__global__ __launch_bounds__(1024) void finalize(
        const float* __restrict__ S, const float* __restrict__ Dd,
        float* __restrict__ out) {
    const int t = threadIdx.x;
    float s = 0.0f;
    for (int i = t; i < N_ROWS; i += 1024) s += Dd[i] + logf(S[i]);
    for (int off = 32; off; off >>= 1) s += __shfl_down(s, off);
    __shared__ float wsum[16];
    if ((t & 63) == 0) wsum[t >> 6] = s;
    __syncthreads();
    if (t == 0) {
        float acc = 0.0f;
#pragma unroll
        for (int w = 0; w < 16; w++) acc += wsum[w];
        out[0] = acc * (1.0f / N_ROWS);
    }
}

// ---------------- fallback (undersized workspace): naive fp32 --------------------
__global__ void zero_out1(float* __restrict__ out) {
    if (threadIdx.x == 0 && blockIdx.x == 0) out[0] = 0.0f;
}
__global__ void naive_row(const float* __restrict__ A, const float* __restrict__ P,
                          float* __restrict__ out) {
    __shared__ float arow[D_DIM];
    const int i = blockIdx.x, t = threadIdx.x;
    for (int c = t; c < D_DIM; c += 256) arow[c] = A[(size_t)i * D_DIM + c];
    __syncthreads();
    float sumexp = 0.0f, ddiag = 0.0f;
    for (int j = t; j < N_ROWS; j += 256) {
        const float* p = P + (size_t)j * D_DIM;
        float d2 = 0.0f;
        for (int c = 0; c < D_DIM; c++) { float df = arow[c] - p[c]; d2 += df * df; }
        float dist = sqrtf(fmaxf(d2, 0.0f) + 1e-12f);
        if (j == i) ddiag = dist;
        sumexp += __expf(-dist);
    }
    for (int off = 32; off; off >>= 1) {
        sumexp += __shfl_down(sumexp, off);
        ddiag  += __shfl_down(ddiag, off);
    }
    __shared__ float w1[4], w2[4];
    if ((t & 63) == 0) { w1[t >> 6] = sumexp; w2[t >> 6] = ddiag; }
    __syncthreads();
    if (t == 0) {
        float se = w1[0] + w1[1] + w1[2] + w1[3];
        float dd = w2[0] + w2[1] + w2[2] + w2[3];
        atomicAdd(out, (dd + logf(se)) * (1.0f / N_ROWS));
    }
}

extern "C" void kernel_launch(void* const* d_in, const int* in_sizes, int n_in,
                              void* d_out, int out_size, void* d_ws, size_t ws_size,
                              hipStream_t stream) {
    const float* A = (const float*)d_in[0];
    const float* P = (const float*)d_in[1];
    float* out = (float*)d_out;

    const size_t F8_BYTES = (size_t)N_ROWS * D_DIM;          // 3145728 per matrix
    const size_t V_BYTES  = (size_t)N_ROWS * sizeof(float);  // 16384
    const size_t NEED = 2 * F8_BYTES + 4 * V_BYTES;

    if (ws_size >= NEED) {
        char* ws = (char*)d_ws;
        uint8_t* A8 = (uint8_t*)(ws);
        uint8_t* P8 = (uint8_t*)(ws + F8_BYTES);
        float* a2 = (float*)(ws + 2 * F8_BYTES);
        float* p2 = (float*)(ws + 2 * F8_BYTES + V_BYTES);
        float* S  = (float*)(ws + 2 * F8_BYTES + 2 * V_BYTES);
        float* Dd = (float*)(ws + 2 * F8_BYTES + 3 * V_BYTES);

        hipLaunchKernelGGL(cvt_norms, dim3(N_ROWS / 4, 2), dim3(256), 0, stream,
                           A, P, A8, P8, a2, p2, S);
        hipLaunchKernelGGL(gemm_fused, dim3(512), dim3(512), 0, stream,
                           A8, P8, a2, p2, S, Dd);
        hipLaunchKernelGGL(finalize, dim3(1), dim3(1024), 0, stream, S, Dd, out);
    } else {
        hipLaunchKernelGGL(zero_out1, dim3(1), dim3(64), 0, stream, out);
        hipLaunchKernelGGL(naive_row, dim3(N_ROWS), dim3(256), 0, stream, A, P, out);
    }
}